// Round 2
// baseline (77.336 us; speedup 1.0000x reference)
//
#include <hip/hip_runtime.h>

// QuanvLayer: 4-qubit circuit per patch.
// Circuit: RY(pi*x_q) encode; [RX(p0),RY(p1),RZ(p2),H]; CNOT ring; RY(p3..p6); measure <Z_q>.
// Closed form used:
//  - product state through layer 1 (v0 complex, v1 real, v2 complex, v3 real)
//  - CNOT ring = basis permutation: amp[b0b1b2b3] = v0[b0^b3] v1[b1^b0^b3] v2[b2^b1] v3[b3^b2]
//  - final RY folded into measurement: out_q = cos(p_{3+q})<Z_q> - sin(p_{3+q})<X_q>
//    (RY^† Z RY = cosθ Z - sinθ X; other-qubit unitaries don't change reduced density of q)

__global__ __launch_bounds__(256) void quanv_kernel(
    const float* __restrict__ x,    // [N,4] angles in [0,1)
    const float* __restrict__ prm,  // [7]
    float* __restrict__ out,        // [N,4]
    int n)
{
    int tid = blockIdx.x * 256 + threadIdx.x;
    if (tid >= n) return;

    // ---- per-thread param trig (uniform across wave; amortize later if VALU-bound)
    float S0, C0, S1, C1, S2, C2;
    __sincosf(prm[0] * 0.5f, &S0, &C0);  // RX q0 half-angle
    __sincosf(prm[1] * 0.5f, &S1, &C1);  // RY q1 half-angle
    __sincosf(prm[2] * 0.5f, &S2, &C2);  // RZ q2 half-angle
    float Sf0, Cf0, Sf1, Cf1, Sf2, Cf2, Sf3, Cf3;  // final RY, FULL angle
    __sincosf(prm[3], &Sf0, &Cf0);
    __sincosf(prm[4], &Sf1, &Cf1);
    __sincosf(prm[5], &Sf2, &Cf2);
    __sincosf(prm[6], &Sf3, &Cf3);

    const float4 xv = reinterpret_cast<const float4*>(x)[tid];

    // ---- encoding RY(pi*x): qubit q state = (cos(pi x/2), sin(pi x/2))
    const float HPI = 1.5707963267948966f;
    float e0s, e0c, e1s, e1c, e2s, e2c, e3s, e3c;
    __sincosf(xv.x * HPI, &e0s, &e0c);
    __sincosf(xv.y * HPI, &e1s, &e1c);
    __sincosf(xv.z * HPI, &e2s, &e2c);
    __sincosf(xv.w * HPI, &e3s, &e3c);

    // ---- layer 1 single-qubit gates (still product state)
    // q0: RX(p0) on (e0c,e0s): [[C,-iS],[-iS,C]]
    float v00r = C0 * e0c, v00i = -S0 * e0s;
    float v01r = C0 * e0s, v01i = -S0 * e0c;
    // q1: RY(p1) — real
    float v10 = C1 * e1c - S1 * e1s;
    float v11 = S1 * e1c + C1 * e1s;
    // q2: RZ(p2): diag(e^{-ip/2}, e^{+ip/2})
    float v20r = e2c * C2, v20i = -e2c * S2;
    float v21r = e2s * C2, v21i =  e2s * S2;
    // q3: H — real
    const float RS2 = 0.70710678118654752f;
    float v30 = (e3c + e3s) * RS2;
    float v31 = (e3c - e3s) * RS2;

    // ---- pair products t = v0 (x) v1 (v1 real), u = v2 (x) v3 (v3 real)
    float t00r = v00r * v10, t00i = v00i * v10;
    float t01r = v00r * v11, t01i = v00i * v11;
    float t10r = v01r * v10, t10i = v01i * v10;
    float t11r = v01r * v11, t11i = v01i * v11;
    float u00r = v20r * v30, u00i = v20i * v30;
    float u01r = v20r * v31, u01i = v20i * v31;
    float u10r = v21r * v30, u10i = v21i * v30;
    float u11r = v21r * v31, u11i = v21i * v31;

    // ---- 16 post-CNOT amplitudes: amp[b] = t[b0^b3][b1^b0^b3] * u[b2^b1][b3^b2]
#define CMUL(dr, di, ar, ai, br, bi) \
    float dr = (ar) * (br) - (ai) * (bi); \
    float di = (ar) * (bi) + (ai) * (br);
    CMUL(a0r, a0i,  t00r, t00i, u00r, u00i)   // 0000
    CMUL(a1r, a1i,  t11r, t11i, u01r, u01i)   // 0001
    CMUL(a2r, a2i,  t00r, t00i, u11r, u11i)   // 0010
    CMUL(a3r, a3i,  t11r, t11i, u10r, u10i)   // 0011
    CMUL(a4r, a4i,  t01r, t01i, u10r, u10i)   // 0100
    CMUL(a5r, a5i,  t10r, t10i, u11r, u11i)   // 0101
    CMUL(a6r, a6i,  t01r, t01i, u01r, u01i)   // 0110
    CMUL(a7r, a7i,  t10r, t10i, u00r, u00i)   // 0111
    CMUL(a8r, a8i,  t11r, t11i, u00r, u00i)   // 1000
    CMUL(a9r, a9i,  t00r, t00i, u01r, u01i)   // 1001
    CMUL(a10r, a10i, t11r, t11i, u11r, u11i)  // 1010
    CMUL(a11r, a11i, t00r, t00i, u10r, u10i)  // 1011
    CMUL(a12r, a12i, t10r, t10i, u10r, u10i)  // 1100
    CMUL(a13r, a13i, t01r, t01i, u11r, u11i)  // 1101
    CMUL(a14r, a14i, t10r, t10i, u01r, u01i)  // 1110
    CMUL(a15r, a15i, t01r, t01i, u00r, u00i)  // 1111
#undef CMUL

    // ---- probabilities  (macro param renamed to k so literal r/i suffixes survive ##)
#define PROB(k) float p##k = a##k##r * a##k##r + a##k##i * a##k##i;
    PROB(0) PROB(1) PROB(2) PROB(3) PROB(4) PROB(5) PROB(6) PROB(7)
    PROB(8) PROB(9) PROB(10) PROB(11) PROB(12) PROB(13) PROB(14) PROB(15)
#undef PROB

    // ---- <Z_q> sums (qubit 0 = MSB of the 4-bit index)
    float zpA = (p0 + p1) + (p2 + p3);
    float zpB = (p4 + p5) + (p6 + p7);
    float zpC = (p8 + p9) + (p10 + p11);
    float zpD = (p12 + p13) + (p14 + p15);
    float z0 = (zpA + zpB) - (zpC + zpD);
    float z1 = (zpA + zpC) - (zpB + zpD);
    float z2 = ((p0 + p1) + (p4 + p5) + (p8 + p9) + (p12 + p13))
             - ((p2 + p3) + (p6 + p7) + (p10 + p11) + (p14 + p15));
    float z3 = ((p0 + p2) + (p4 + p6) + (p8 + p10) + (p12 + p14))
             - ((p1 + p3) + (p5 + p7) + (p9 + p11) + (p13 + p15));

    // ---- <X_q>/2 sums: pairs differing in bit q  (params m,n — not i/j/r)
#define DOT(m, n) (a##m##r * a##n##r + a##m##i * a##n##i)
    float xs0 = DOT(0, 8) + DOT(1, 9) + DOT(2, 10) + DOT(3, 11)
              + DOT(4, 12) + DOT(5, 13) + DOT(6, 14) + DOT(7, 15);
    float xs1 = DOT(0, 4) + DOT(1, 5) + DOT(2, 6) + DOT(3, 7)
              + DOT(8, 12) + DOT(9, 13) + DOT(10, 14) + DOT(11, 15);
    float xs2 = DOT(0, 2) + DOT(1, 3) + DOT(4, 6) + DOT(5, 7)
              + DOT(8, 10) + DOT(9, 11) + DOT(12, 14) + DOT(13, 15);
    float xs3 = DOT(0, 1) + DOT(2, 3) + DOT(4, 5) + DOT(6, 7)
              + DOT(8, 9) + DOT(10, 11) + DOT(12, 13) + DOT(14, 15);
#undef DOT

    // ---- fold final RY layer into measurement: out = cosθ·Z - sinθ·(2·xs)
    float4 o;
    o.x = Cf0 * z0 - 2.0f * Sf0 * xs0;
    o.y = Cf1 * z1 - 2.0f * Sf1 * xs1;
    o.z = Cf2 * z2 - 2.0f * Sf2 * xs2;
    o.w = Cf3 * z3 - 2.0f * Sf3 * xs3;
    reinterpret_cast<float4*>(out)[tid] = o;
}

extern "C" void kernel_launch(void* const* d_in, const int* in_sizes, int n_in,
                              void* d_out, int out_size, void* d_ws, size_t ws_size,
                              hipStream_t stream) {
    const float* x   = (const float*)d_in[0];   // [2048*3*196, 4] float32
    const float* prm = (const float*)d_in[1];   // [7] float32
    float* out = (float*)d_out;                 // [N, 4] float32 (same flat order as input patches)
    int n = in_sizes[0] / 4;                    // 1,204,224 patches
    int blocks = (n + 255) / 256;               // 4704
    quanv_kernel<<<blocks, 256, 0, stream>>>(x, prm, out, n);
}

// Round 3
// 72.145 us; speedup vs baseline: 1.0720x; 1.0720x over previous
//
#include <hip/hip_runtime.h>

// QuanvLayer — closed form via Heisenberg picture.
//
// Circuit: RY(pi*x_q) encode; layer1 = [RX(p0), RY(p1), RZ(p2), H]; CNOT ring
// (0->1,1->2,2->3,3->0); final RY(p3..p6); measure <Z_q>.
//
// Final RY folded into measurement: out_q = cos(pf_q)<Z_q> - sin(pf_q)<X_q> (post-CNOT).
// CNOT ring conjugated backward (U = C30 C23 C12 C01; CNOT Pauli map is sign-free):
//   <Z0> -> Z1 Z2 Z3      <X0> -> X0 X1
//   <Z1> -> Z0 Z1         <X1> -> X1 X2
//   <Z2> -> Z0 Z1 Z2      <X2> -> X2 X3
//   <Z3> -> Z0 Z1 Z2 Z3   <X3> -> X3 X0 X1
// evaluated on the layer-1 PRODUCT state, so every term is a product of
// single-qubit Bloch components:
//   z0 = cos p0 * cos(pi x0)        x0 = sin(pi x0)          (RX preserves X)
//   z1 = cos(pi x1 + p1)            x1 = sin(pi x1 + p1)     (RY adds angles)
//   z2 = cos(pi x2)                 x2 = cos p2 * sin(pi x2) (RZ preserves Z)
//   z3 = sin(pi x3)                 x3 = cos(pi x3)          (H swaps X<->Z)
// Verified vs direct state evolution on 3 hand-worked cases + round-2 kernel
// (algebraically identical; round-2 passed end-to-end).
//
// v_sin_f32/v_cos_f32 take REVOLUTIONS: sin(pi*x) = v_sin(0.5*x), x in [0,1)
// -> in hardware range, zero range-reduction. Same for params (p in [0,pi)).

__global__ __launch_bounds__(256) void quanv_kernel(
    const float4* __restrict__ x,   // [N] patches of 4 angles in [0,1)
    const float* __restrict__ prm,  // [7]
    float4* __restrict__ out,       // [N] <Z_q> outputs
    int n)
{
    int tid = blockIdx.x * 256 + threadIdx.x;
    if (tid >= n) return;

    const float INV_2PI = 0.15915494309189535f;  // rad -> revolutions

    // ---- wave-uniform param trig (native hw sin/cos; args < 0.5 rev)
    float A   = __builtin_amdgcn_cosf(prm[0] * INV_2PI);  // cos p0
    float Cp1 = __builtin_amdgcn_cosf(prm[1] * INV_2PI);
    float Sp1 = __builtin_amdgcn_sinf(prm[1] * INV_2PI);
    float Bc  = __builtin_amdgcn_cosf(prm[2] * INV_2PI);  // cos p2
    float Cf0 = __builtin_amdgcn_cosf(prm[3] * INV_2PI);
    float Sf0 = __builtin_amdgcn_sinf(prm[3] * INV_2PI);
    float Cf1 = __builtin_amdgcn_cosf(prm[4] * INV_2PI);
    float Sf1 = __builtin_amdgcn_sinf(prm[4] * INV_2PI);
    float Cf2 = __builtin_amdgcn_cosf(prm[5] * INV_2PI);
    float Sf2 = __builtin_amdgcn_sinf(prm[5] * INV_2PI);
    float Cf3 = __builtin_amdgcn_cosf(prm[6] * INV_2PI);
    float Sf3 = __builtin_amdgcn_sinf(prm[6] * INV_2PI);

    const float4 xv = x[tid];

    // ---- full-angle trig of pi*x_q: rev = 0.5*x
    float c0 = __builtin_amdgcn_cosf(0.5f * xv.x);
    float s0 = __builtin_amdgcn_sinf(0.5f * xv.x);
    float c1 = __builtin_amdgcn_cosf(0.5f * xv.y);
    float s1 = __builtin_amdgcn_sinf(0.5f * xv.y);
    float c2 = __builtin_amdgcn_cosf(0.5f * xv.z);
    float s2 = __builtin_amdgcn_sinf(0.5f * xv.z);
    float c3 = __builtin_amdgcn_cosf(0.5f * xv.w);
    float s3 = __builtin_amdgcn_sinf(0.5f * xv.w);

    // ---- qubit-1 Bloch after RY(p1): angle addition
    float z1 = c1 * Cp1 - s1 * Sp1;   // cos(pi x1 + p1)
    float x1 = s1 * Cp1 + c1 * Sp1;   // sin(pi x1 + p1)

    // ---- shared products
    float P = A * c0 * z1;            // z0*z1
    float R = P * c2;                 // z0*z1*z2
    float Q = z1 * c2;                // z1*z2
    float T = s0 * x1;                // x0*x1
    float W = Bc * s2;                // x2

    float4 o;
    o.x = Cf0 * (Q * s3) - Sf0 * T;          // z1 z2 z3 | x0 x1
    o.y = Cf1 * P        - Sf1 * (x1 * W);   // z0 z1    | x1 x2
    o.z = Cf2 * R        - Sf2 * (W * c3);   // z0 z1 z2 | x2 x3
    o.w = Cf3 * (R * s3) - Sf3 * (c3 * T);   // z0..z3   | x3 x0 x1
    out[tid] = o;
}

extern "C" void kernel_launch(void* const* d_in, const int* in_sizes, int n_in,
                              void* d_out, int out_size, void* d_ws, size_t ws_size,
                              hipStream_t stream) {
    const float4* x  = (const float4*)d_in[0];  // [1204224, 4] f32
    const float* prm = (const float*)d_in[1];   // [7] f32
    float4* out = (float4*)d_out;               // [1204224, 4] f32
    int n = in_sizes[0] / 4;
    int blocks = (n + 255) / 256;               // 4704
    quanv_kernel<<<blocks, 256, 0, stream>>>(x, prm, out, n);
}